// Round 2
// baseline (666.774 us; speedup 1.0000x reference)
//
#include <hip/hip_runtime.h>
#include <stdint.h>

typedef float  f32x4  __attribute__((ext_vector_type(4)));
typedef short  bf16x8 __attribute__((ext_vector_type(8)));
typedef unsigned short u16;
typedef unsigned short u16x8 __attribute__((ext_vector_type(8)));

// async global->LDS, 16B per lane; LDS dest is wave-uniform base + lane*16
#define GLD16(gsrc, ldst) \
  __builtin_amdgcn_global_load_lds((const __attribute__((address_space(1))) uint32_t*)(gsrc), \
                                   (__attribute__((address_space(3))) uint32_t*)(ldst), 16, 0, 0)

static __device__ __forceinline__ u16 f2bf(float f) {
  union { float f; uint32_t u; } v; v.f = f;
  uint32_t r = (v.u + 0x7FFFu + ((v.u >> 16) & 1u)) >> 16;  // RTNE
  return (u16)r;
}

// ---------------- P0: all 4x4 matrices + alpha -> consts[80] ----------------
// consts[0:16]  Hpre_attn softmax (p-major [p][u])
// consts[16:32] Hpre_hyb  softmax
// consts[32:48] Rcomb[p][t] = a*sink_a[p][t] + (1-a)*sink_h[p][t]
// consts[48:64] Ca[t][s] = a*scales_a[t]*softmax(Hpost_a)[t][s]
// consts[64:80] Ch[t][s] = (1-a)*scales_h[t]*softmax(Hpost_h)[t][s]
__global__ void k_prep(const float* __restrict__ HpreA_l, const float* __restrict__ HpreH_l,
                       const float* __restrict__ HresA_l, const float* __restrict__ HpostA_l,
                       const float* __restrict__ scalesA,
                       const float* __restrict__ HresH_l, const float* __restrict__ HpostH_l,
                       const float* __restrict__ scalesH,
                       const float* __restrict__ crossmix, float* __restrict__ consts) {
  if (threadIdx.x != 0) return;
  float alpha = 1.0f / (1.0f + expf(-crossmix[0]));
  float Pa[16], Ph[16], SA[16], SH[16], QA[16], QH[16];
  const float* Ls[4] = {HpreA_l, HpreH_l, HpostA_l, HpostH_l};
  float* Os[4] = {Pa, Ph, QA, QH};
  for (int m = 0; m < 4; ++m) {
    for (int r = 0; r < 4; ++r) {
      float mx = Ls[m][r*4+0];
      for (int c = 1; c < 4; ++c) mx = fmaxf(mx, Ls[m][r*4+c]);
      float s = 0.f;
      for (int c = 0; c < 4; ++c) { float e = expf(Ls[m][r*4+c] - mx); Os[m][r*4+c] = e; s += e; }
      for (int c = 0; c < 4; ++c) Os[m][r*4+c] /= s;
    }
  }
  const float* Lr[2] = {HresA_l, HresH_l};
  float* Or[2] = {SA, SH};
  for (int m = 0; m < 2; ++m) {
    float mx = Lr[m][0];
    for (int i = 1; i < 16; ++i) mx = fmaxf(mx, Lr[m][i]);
    for (int i = 0; i < 16; ++i) Or[m][i] = expf(Lr[m][i] - mx);
    for (int it = 0; it < 20; ++it) {
      for (int r = 0; r < 4; ++r) {
        float s = 1e-8f;
        for (int c = 0; c < 4; ++c) s += Or[m][r*4+c];
        for (int c = 0; c < 4; ++c) Or[m][r*4+c] /= s;
      }
      for (int c = 0; c < 4; ++c) {
        float s = 1e-8f;
        for (int r = 0; r < 4; ++r) s += Or[m][r*4+c];
        for (int r = 0; r < 4; ++r) Or[m][r*4+c] /= s;
      }
    }
  }
  for (int i = 0; i < 16; ++i) consts[i]      = Pa[i];
  for (int i = 0; i < 16; ++i) consts[16 + i] = Ph[i];
  for (int i = 0; i < 16; ++i) consts[32 + i] = alpha * SA[i] + (1.0f - alpha) * SH[i];
  for (int t = 0; t < 4; ++t)
    for (int s = 0; s < 4; ++s) {
      consts[48 + t*4 + s] = alpha * scalesA[t] * QA[t*4 + s];
      consts[64 + t*4 + s] = (1.0f - alpha) * scalesH[t] * QH[t*4 + s];
    }
}

// ---------------- P0b: folded output bias [2048] ----------------
__global__ void k_bias(const float* __restrict__ bA, const float* __restrict__ bH,
                       const float* __restrict__ consts, float* __restrict__ bias) {
  int j = blockIdx.x * 256 + threadIdx.x;     // 0..2047
  int t = j >> 9, d = j & 511;
  float acc = 0.f;
  for (int s = 0; s < 4; ++s)
    acc += consts[48 + t*4 + s] * bA[s*512 + d] + consts[64 + t*4 + s] * bH[s*512 + d];
  bias[j] = acc;
}

// ---------------- P1a: fold 4x4 mixes into weights; f32 temp [4096][2048] ----------------
// temp[half*2048 + p*512 + da][t*512 + d] = sum_{u,s} Hpre[p,u] * W[u*512+da, s*512+d] * C[t,s]
//   half=1 additionally adds Rcomb[p][t] * delta(da == d)   (residual fold)
__global__ __launch_bounds__(256) void k_fold(const float* __restrict__ Wa,
                                              const float* __restrict__ Wh,
                                              const float* __restrict__ consts,
                                              float* __restrict__ temp) {
  int bid  = blockIdx.x;                 // 0..2047
  int da   = bid >> 2;                   // 0..511
  int half = (bid >> 1) & 1;
  int j4   = (bid & 1) * 256 + threadIdx.x;  // 0..511  (output col / 4)
  int t    = j4 >> 7;
  int dcol = (j4 & 127) * 4;
  const float* W  = half ? Wh : Wa;
  const float* Hp = consts + (half ? 16 : 0);
  const float* C  = consts + (half ? 64 : 48);
  float c_t[4];
  for (int s = 0; s < 4; ++s) c_t[s] = C[t*4 + s];
  f32x4 acc[4];
  for (int p = 0; p < 4; ++p) for (int e = 0; e < 4; ++e) acc[p][e] = 0.f;
  #pragma unroll
  for (int u = 0; u < 4; ++u) {
    float hp[4];
    for (int p = 0; p < 4; ++p) hp[p] = Hp[p*4 + u];
    #pragma unroll
    for (int s = 0; s < 4; ++s) {
      f32x4 wv = *(const f32x4*)&W[(size_t)(u*512 + da) * 2048 + s*512 + dcol];
      float cs = c_t[s];
      for (int p = 0; p < 4; ++p) acc[p] += (hp[p] * cs) * wv;
    }
  }
  if (half) {
    int e = da - dcol;
    if (e >= 0 && e < 4)
      for (int p = 0; p < 4; ++p) acc[p][e] += consts[32 + p*4 + t];
  }
  for (int p = 0; p < 4; ++p)
    *(f32x4*)&temp[(size_t)(half*2048 + p*512 + da) * 2048 + j4*4] = acc[p];
}

// ---------------- P1T: transpose temp [4096][2048] f32 -> Wc_t [2048][4096] bf16 ----------------
__global__ __launch_bounds__(256) void k_transpose(const float* __restrict__ temp,
                                                   u16* __restrict__ Bt) {
  __shared__ float tile[64][65];
  int r0 = blockIdx.x * 64;   // rows of temp (0..4095)
  int c0 = blockIdx.y * 64;   // cols of temp (0..2047)
  int tid = threadIdx.x;
  int lr = tid >> 4;          // 0..15
  int lc = (tid & 15) * 4;    // 0..60
  #pragma unroll
  for (int i = 0; i < 4; ++i) {
    int row = lr + i * 16;
    f32x4 v = *(const f32x4*)&temp[(size_t)(r0 + row) * 2048 + c0 + lc];
    tile[row][lc+0] = v[0]; tile[row][lc+1] = v[1];
    tile[row][lc+2] = v[2]; tile[row][lc+3] = v[3];
  }
  __syncthreads();
  #pragma unroll
  for (int k = 0; k < 4; ++k) {
    int jj = lr + k * 16;     // col of temp = row of Bt
    ushort4 o;
    o.x = f2bf(tile[lc+0][jj]); o.y = f2bf(tile[lc+1][jj]);
    o.z = f2bf(tile[lc+2][jj]); o.w = f2bf(tile[lc+3][jj]);
    *(ushort4*)&Bt[(size_t)(c0 + jj) * 4096 + r0 + lc] = o;
  }
}

// ---------------- P2: per-row LN stats + materialize A bf16 [16384][4096] ----------------
// cols 0..2047 = layernorm(x_row), cols 2048..4095 = raw x_row
__global__ __launch_bounds__(256) void k_rowprep(const float* __restrict__ x,
                                                 const float* __restrict__ gamma,
                                                 const float* __restrict__ beta,
                                                 u16* __restrict__ A) {
  int m = blockIdx.x;
  int tid = threadIdx.x;
  const float* row = x + (size_t)m * 2048;
  f32x4 v0 = *(const f32x4*)&row[tid*8];
  f32x4 v1 = *(const f32x4*)&row[tid*8 + 4];
  float s1 = v0[0]+v0[1]+v0[2]+v0[3] + v1[0]+v1[1]+v1[2]+v1[3];
  float s2 = v0[0]*v0[0]+v0[1]*v0[1]+v0[2]*v0[2]+v0[3]*v0[3]
           + v1[0]*v1[0]+v1[1]*v1[1]+v1[2]*v1[2]+v1[3]*v1[3];
  for (int off = 32; off > 0; off >>= 1) {
    s1 += __shfl_down(s1, off);
    s2 += __shfl_down(s2, off);
  }
  __shared__ float red[8];
  int w = tid >> 6, l = tid & 63;
  if (l == 0) { red[w] = s1; red[4 + w] = s2; }
  __syncthreads();
  float t1 = red[0]+red[1]+red[2]+red[3];
  float t2 = red[4]+red[5]+red[6]+red[7];
  float mu = t1 * (1.0f/2048.0f);
  float var = t2 * (1.0f/2048.0f) - mu*mu;
  float rstd = rsqrtf(var + 1e-5f);
  f32x4 g0 = *(const f32x4*)&gamma[tid*8];
  f32x4 g1 = *(const f32x4*)&gamma[tid*8 + 4];
  f32x4 b0 = *(const f32x4*)&beta[tid*8];
  f32x4 b1 = *(const f32x4*)&beta[tid*8 + 4];
  u16x8 pn, pr;
  #pragma unroll
  for (int e = 0; e < 4; ++e) {
    pr[e]   = f2bf(v0[e]);
    pr[4+e] = f2bf(v1[e]);
    pn[e]   = f2bf((v0[e] - mu) * rstd * g0[e] + b0[e]);
    pn[4+e] = f2bf((v1[e] - mu) * rstd * g1[e] + b1[e]);
  }
  *(u16x8*)&A[(size_t)m * 4096 + tid*8]        = pn;   // normed half (K 0..2047)
  *(u16x8*)&A[(size_t)m * 4096 + 2048 + tid*8] = pr;   // raw half    (K 2048..4095)
}

// ---------------- GEMM: out[16384][2048] = A[16384][4096] @ Wc_t^T + bias ----------------
// m97 structure: 128x128 tile, BK=32, 4 waves (2x2), 16x16x32 bf16 MFMA,
// global_load_lds width-16 staging for both operands.
__global__ __launch_bounds__(256) void k_gemm(const u16* __restrict__ A,
                                              const u16* __restrict__ B,   // [2048][4096] N-major
                                              const float* __restrict__ bias,
                                              float* __restrict__ out) {
  __shared__ __align__(16) u16 ldsA[128 * 32];
  __shared__ __align__(16) u16 ldsB[128 * 32];
  int bid = blockIdx.x;
  int mt = bid >> 4, nt = bid & 15;
  int m0 = mt * 128, n0 = nt * 128;
  int tid = threadIdx.x;
  int l = tid & 63, w = tid >> 6;
  int lr = l & 15, lk = l >> 4;
  int wm = (w >> 1) * 64, wn = (w & 1) * 64;
  const char* gA = (const char*)A + (size_t)m0 * 8192;  // row stride 4096*2B
  const char* gB = (const char*)B + (size_t)n0 * 8192;
  char* lA = (char*)ldsA;
  char* lB = (char*)ldsB;

  f32x4 acc[4][4];
  for (int mi = 0; mi < 4; ++mi)
    for (int ni = 0; ni < 4; ++ni)
      for (int r = 0; r < 4; ++r) acc[mi][ni][r] = 0.f;

  for (int kt = 0; kt < 128; ++kt) {
    #pragma unroll
    for (int c = 0; c < 2; ++c) {
      int ob = (w * 2 + c) * 1024;          // wave-uniform LDS base
      int o  = ob + l * 16;                 // linear byte in 8KiB tile
      int rw = o >> 6;                      // tile row (64B per row)
      int kb = o & 63;                      // byte within row
      GLD16(gA + (size_t)rw * 8192 + kt * 64 + kb, lA + ob);
      GLD16(gB + (size_t)rw * 8192 + kt * 64 + kb, lB + ob);
    }
    __syncthreads();
    bf16x8 af[4], bfr[4];
    #pragma unroll
    for (int mi = 0; mi < 4; ++mi)
      af[mi] = *(const bf16x8*)(lA + (wm + mi*16 + lr) * 64 + lk * 16);
    #pragma unroll
    for (int ni = 0; ni < 4; ++ni)
      bfr[ni] = *(const bf16x8*)(lB + (wn + ni*16 + lr) * 64 + lk * 16);
    #pragma unroll
    for (int mi = 0; mi < 4; ++mi)
      #pragma unroll
      for (int ni = 0; ni < 4; ++ni)
        acc[mi][ni] = __builtin_amdgcn_mfma_f32_16x16x32_bf16(af[mi], bfr[ni], acc[mi][ni], 0, 0, 0);
    __syncthreads();
  }

  #pragma unroll
  for (int ni = 0; ni < 4; ++ni) {
    int col = n0 + wn + ni*16 + lr;
    float bc = bias[col];
    #pragma unroll
    for (int mi = 0; mi < 4; ++mi)
      #pragma unroll
      for (int r = 0; r < 4; ++r) {
        int row = m0 + wm + mi*16 + lk*4 + r;
        out[(size_t)row * 2048 + col] = acc[mi][ni][r] + bc;
      }
  }
}

// ---------------- emergency: encode ws_size(MB) into d_out so failure is diagnosable ----------------
__global__ void k_report(float* out, float v) {
  out[blockIdx.x * 256 + threadIdx.x] = v;
}

extern "C" void kernel_launch(void* const* d_in, const int* in_sizes, int n_in,
                              void* d_out, int out_size, void* d_ws, size_t ws_size,
                              hipStream_t stream) {
  (void)in_sizes; (void)n_in; (void)out_size;
  const float* x       = (const float*)d_in[0];
  const float* gamma   = (const float*)d_in[1];
  const float* beta    = (const float*)d_in[2];
  const float* Wa      = (const float*)d_in[3];
  const float* ba      = (const float*)d_in[4];
  const float* Wh      = (const float*)d_in[5];
  const float* bh      = (const float*)d_in[6];
  const float* HpreA   = (const float*)d_in[7];
  const float* HpreH   = (const float*)d_in[8];
  const float* HresA   = (const float*)d_in[9];
  const float* HpostA  = (const float*)d_in[10];
  const float* scalesA = (const float*)d_in[11];
  const float* HresH   = (const float*)d_in[12];
  const float* HpostH  = (const float*)d_in[13];
  const float* scalesH = (const float*)d_in[14];
  const float* cm      = (const float*)d_in[15];
  float* out = (float*)d_out;

  const size_t OFF_CONST = 0;
  const size_t OFF_BIAS  = 4096;
  const size_t OFF_B     = (size_t)1 << 20;    // Wc_t bf16 [2048][4096] = 16 MiB
  const size_t OFF_A     = (size_t)17 << 20;   // A bf16 [16384][4096] = 128 MiB (first 32MiB doubles as f32 fold temp)
  const size_t NEED      = OFF_A + ((size_t)128 << 20);

  if (ws_size < NEED) {
    k_report<<<4, 256, 0, stream>>>(out, (float)(ws_size >> 20));
    return;
  }

  float* consts = (float*)((char*)d_ws + OFF_CONST);
  float* bias   = (float*)((char*)d_ws + OFF_BIAS);
  u16*   Bt     = (u16*)((char*)d_ws + OFF_B);
  u16*   Am     = (u16*)((char*)d_ws + OFF_A);
  float* temp   = (float*)((char*)d_ws + OFF_A);   // reused before Am is written

  k_prep<<<1, 64, 0, stream>>>(HpreA, HpreH, HresA, HpostA, scalesA,
                               HresH, HpostH, scalesH, cm, consts);
  k_bias<<<8, 256, 0, stream>>>(ba, bh, consts, bias);
  k_fold<<<2048, 256, 0, stream>>>(Wa, Wh, consts, temp);
  k_transpose<<<dim3(64, 32), 256, 0, stream>>>(temp, Bt);
  k_rowprep<<<16384, 256, 0, stream>>>(x, gamma, beta, Am);   // overwrites temp area — must follow k_transpose
  k_gemm<<<2048, 256, 0, stream>>>(Am, Bt, bias, out);
}

// Round 4
// 642.497 us; speedup vs baseline: 1.0378x; 1.0378x over previous
//
#include <hip/hip_runtime.h>
#include <stdint.h>

typedef float  f32x4  __attribute__((ext_vector_type(4)));
typedef short  bf16x8 __attribute__((ext_vector_type(8)));
typedef unsigned short u16;
typedef unsigned short u16x8 __attribute__((ext_vector_type(8)));

// async global->LDS, 16B per lane; LDS dest is wave-uniform base + lane*16
#define GLD16(gsrc, ldst) \
  __builtin_amdgcn_global_load_lds((const __attribute__((address_space(1))) uint32_t*)(gsrc), \
                                   (__attribute__((address_space(3))) uint32_t*)(ldst), 16, 0, 0)

static __device__ __forceinline__ u16 f2bf(float f) {
  union { float f; uint32_t u; } v; v.f = f;
  uint32_t r = (v.u + 0x7FFFu + ((v.u >> 16) & 1u)) >> 16;  // RTNE
  return (u16)r;
}

// ---------------- P0: 4x4 matrices + alpha -> consts[80], plus folded bias [2048] ----------------
// consts[0:16]  Hpre_attn softmax (p-major [p][u])
// consts[16:32] Hpre_hyb  softmax
// consts[32:48] Rcomb[p][t] = a*sink_a[p][t] + (1-a)*sink_h[p][t]
// consts[48:64] Ca[t][s] = a*scales_a[t]*softmax(Hpost_a)[t][s]
// consts[64:80] Ch[t][s] = (1-a)*scales_h[t]*softmax(Hpost_h)[t][s]
__global__ void k_prepbias(const float* __restrict__ HpreA_l, const float* __restrict__ HpreH_l,
                           const float* __restrict__ HresA_l, const float* __restrict__ HpostA_l,
                           const float* __restrict__ scalesA,
                           const float* __restrict__ HresH_l, const float* __restrict__ HpostH_l,
                           const float* __restrict__ scalesH,
                           const float* __restrict__ crossmix, float* __restrict__ consts,
                           const float* __restrict__ bA, const float* __restrict__ bH,
                           float* __restrict__ bias) {
  __shared__ float sc[80];
  if (threadIdx.x == 0) {
    float alpha = 1.0f / (1.0f + expf(-crossmix[0]));
    float Pa[16], Ph[16], SA[16], SH[16], QA[16], QH[16];
    const float* Ls[4] = {HpreA_l, HpreH_l, HpostA_l, HpostH_l};
    float* Os[4] = {Pa, Ph, QA, QH};
    for (int m = 0; m < 4; ++m) {
      for (int r = 0; r < 4; ++r) {
        float mx = Ls[m][r*4+0];
        for (int c = 1; c < 4; ++c) mx = fmaxf(mx, Ls[m][r*4+c]);
        float s = 0.f;
        for (int c = 0; c < 4; ++c) { float e = expf(Ls[m][r*4+c] - mx); Os[m][r*4+c] = e; s += e; }
        for (int c = 0; c < 4; ++c) Os[m][r*4+c] /= s;
      }
    }
    const float* Lr[2] = {HresA_l, HresH_l};
    float* Or[2] = {SA, SH};
    for (int m = 0; m < 2; ++m) {
      float mx = Lr[m][0];
      for (int i = 1; i < 16; ++i) mx = fmaxf(mx, Lr[m][i]);
      for (int i = 0; i < 16; ++i) Or[m][i] = expf(Lr[m][i] - mx);
      for (int it = 0; it < 20; ++it) {
        for (int r = 0; r < 4; ++r) {
          float s = 1e-8f;
          for (int c = 0; c < 4; ++c) s += Or[m][r*4+c];
          for (int c = 0; c < 4; ++c) Or[m][r*4+c] /= s;
        }
        for (int c = 0; c < 4; ++c) {
          float s = 1e-8f;
          for (int r = 0; r < 4; ++r) s += Or[m][r*4+c];
          for (int r = 0; r < 4; ++r) Or[m][r*4+c] /= s;
        }
      }
    }
    for (int i = 0; i < 16; ++i) sc[i]      = Pa[i];
    for (int i = 0; i < 16; ++i) sc[16 + i] = Ph[i];
    for (int i = 0; i < 16; ++i) sc[32 + i] = alpha * SA[i] + (1.0f - alpha) * SH[i];
    for (int t = 0; t < 4; ++t)
      for (int s = 0; s < 4; ++s) {
        sc[48 + t*4 + s] = alpha * scalesA[t] * QA[t*4 + s];
        sc[64 + t*4 + s] = (1.0f - alpha) * scalesH[t] * QH[t*4 + s];
      }
    for (int i = 0; i < 80; ++i) consts[i] = sc[i];
  }
  __syncthreads();
  #pragma unroll
  for (int k = 0; k < 8; ++k) {
    int j = k*256 + threadIdx.x;     // 0..2047
    int t = j >> 9, d = j & 511;
    float acc = 0.f;
    for (int s = 0; s < 4; ++s)
      acc += sc[48 + t*4 + s] * bA[s*512 + d] + sc[64 + t*4 + s] * bH[s*512 + d];
    bias[j] = acc;
  }
}

// ---------------- P1a: fold 4x4 mixes into weights; f32 temp [4096][2048] ----------------
// temp[half*2048 + p*512 + da][t*512 + d] = sum_{u,s} Hpre[p,u] * W[u*512+da, s*512+d] * C[t,s]
//   half=1 additionally adds Rcomb[p][t] * delta(da == d)   (residual fold)
__global__ __launch_bounds__(256) void k_fold(const float* __restrict__ Wa,
                                              const float* __restrict__ Wh,
                                              const float* __restrict__ consts,
                                              float* __restrict__ temp) {
  int bid  = blockIdx.x;                 // 0..2047
  int da   = bid >> 2;                   // 0..511
  int half = (bid >> 1) & 1;
  int j4   = (bid & 1) * 256 + threadIdx.x;  // 0..511  (output col / 4)
  int t    = j4 >> 7;
  int dcol = (j4 & 127) * 4;
  const float* W  = half ? Wh : Wa;
  const float* Hp = consts + (half ? 16 : 0);
  const float* C  = consts + (half ? 64 : 48);
  float c_t[4];
  for (int s = 0; s < 4; ++s) c_t[s] = C[t*4 + s];
  f32x4 acc[4];
  for (int p = 0; p < 4; ++p) for (int e = 0; e < 4; ++e) acc[p][e] = 0.f;
  #pragma unroll
  for (int u = 0; u < 4; ++u) {
    float hp[4];
    for (int p = 0; p < 4; ++p) hp[p] = Hp[p*4 + u];
    #pragma unroll
    for (int s = 0; s < 4; ++s) {
      f32x4 wv = *(const f32x4*)&W[(size_t)(u*512 + da) * 2048 + s*512 + dcol];
      float cs = c_t[s];
      for (int p = 0; p < 4; ++p) acc[p] += (hp[p] * cs) * wv;
    }
  }
  if (half) {
    int e = da - dcol;
    if (e >= 0 && e < 4)
      for (int p = 0; p < 4; ++p) acc[p][e] += consts[32 + p*4 + t];
  }
  for (int p = 0; p < 4; ++p)
    *(f32x4*)&temp[(size_t)(half*2048 + p*512 + da) * 2048 + j4*4] = acc[p];
}

// ---------------- P1T: transpose temp [4096][2048] f32 -> Wc_t [2048][4096] bf16 ----------------
__global__ __launch_bounds__(256) void k_transpose(const float* __restrict__ temp,
                                                   u16* __restrict__ Bt) {
  __shared__ float tile[64][65];
  int r0 = blockIdx.x * 64;   // rows of temp (0..4095)
  int c0 = blockIdx.y * 64;   // cols of temp (0..2047)
  int tid = threadIdx.x;
  int lr = tid >> 4;          // 0..15
  int lc = (tid & 15) * 4;    // 0..60
  #pragma unroll
  for (int i = 0; i < 4; ++i) {
    int row = lr + i * 16;
    f32x4 v = *(const f32x4*)&temp[(size_t)(r0 + row) * 2048 + c0 + lc];
    tile[row][lc+0] = v[0]; tile[row][lc+1] = v[1];
    tile[row][lc+2] = v[2]; tile[row][lc+3] = v[3];
  }
  __syncthreads();
  #pragma unroll
  for (int k = 0; k < 4; ++k) {
    int jj = lr + k * 16;     // col of temp = row of Bt
    ushort4 o;
    o.x = f2bf(tile[lc+0][jj]); o.y = f2bf(tile[lc+1][jj]);
    o.z = f2bf(tile[lc+2][jj]); o.w = f2bf(tile[lc+3][jj]);
    *(ushort4*)&Bt[(size_t)(c0 + jj) * 4096 + r0 + lc] = o;
  }
}

// ---------------- P2: per-row LN + materialize A bf16 [16384][4096] ----------------
// Wave-per-row: no LDS, no __syncthreads. cols 0..2047 = LN(x), 2048..4095 = raw x.
__global__ __launch_bounds__(256) void k_rowprep(const float* __restrict__ x,
                                                 const float* __restrict__ gamma,
                                                 const float* __restrict__ beta,
                                                 u16* __restrict__ A) {
  int wid = (blockIdx.x * 256 + threadIdx.x) >> 6;   // 0..16383 (row)
  int l = threadIdx.x & 63;
  const float* row = x + (size_t)wid * 2048;
  f32x4 v[8];
  float s1 = 0.f, s2 = 0.f;
  #pragma unroll
  for (int j = 0; j < 8; ++j) {
    v[j] = *(const f32x4*)&row[j*256 + l*4];
    #pragma unroll
    for (int e = 0; e < 4; ++e) { s1 += v[j][e]; s2 += v[j][e]*v[j][e]; }
  }
  #pragma unroll
  for (int off = 32; off; off >>= 1) {
    s1 += __shfl_down(s1, off, 64);
    s2 += __shfl_down(s2, off, 64);
  }
  s1 = __shfl(s1, 0, 64);
  s2 = __shfl(s2, 0, 64);
  float mu   = s1 * (1.0f/2048.0f);
  float var  = s2 * (1.0f/2048.0f) - mu*mu;
  float rstd = rsqrtf(var + 1e-5f);
  u16* An = A + (size_t)wid * 4096;
  #pragma unroll
  for (int j = 0; j < 8; ++j) {
    f32x4 g = *(const f32x4*)&gamma[j*256 + l*4];
    f32x4 b = *(const f32x4*)&beta[j*256 + l*4];
    ushort4 pn, pr;
    pn.x = f2bf((v[j][0]-mu)*rstd*g[0] + b[0]);
    pn.y = f2bf((v[j][1]-mu)*rstd*g[1] + b[1]);
    pn.z = f2bf((v[j][2]-mu)*rstd*g[2] + b[2]);
    pn.w = f2bf((v[j][3]-mu)*rstd*g[3] + b[3]);
    pr.x = f2bf(v[j][0]); pr.y = f2bf(v[j][1]);
    pr.z = f2bf(v[j][2]); pr.w = f2bf(v[j][3]);
    *(ushort4*)&An[j*256 + l*4]        = pn;   // normed half (K 0..2047)
    *(ushort4*)&An[2048 + j*256 + l*4] = pr;   // raw half    (K 2048..4095)
  }
}

// ---------------- GEMM: 256x256 tile, BK=64, 8-phase schedule (T1+T2+T3/T4+T5) ----------------
// out[16384][2048] = A[16384][4096] @ Bt^T + bias.  Bt is [2048][4096] (N-major).
// 512 threads = 8 waves (2 M x 4 N), wave tile 128x64, 16x16x32 bf16 MFMA.
// LDS: per operand 2 dbuf x 2 K-halves x [256 rows][32 k] bf16 (16 KiB each) = 64 KiB; total 128 KiB.
// Swizzle: 16B chunk c within the 64B row XORed with (r>>2)&3 — applied to the pre-swizzled
// global source (global_load_lds writes linearly) and to the ds_read address (involution).
// vmcnt ledger: steady state keeps 8 loads (4 half-tile STAGE pairs) in flight past each guard;
// tail peeled: kt=62 guards are vmcnt(8)/vmcnt(4), kt=63 is vmcnt(0)/none (race fix, R3 audit).

static __device__ __forceinline__ void read4(bf16x8* F, const char* base) {
  #pragma unroll
  for (int i = 0; i < 4; ++i) F[i] = *(const bf16x8*)(base + i*1024);
}
static __device__ __forceinline__ void mfma16(f32x4 (*accq)[4], const bf16x8* Af, const bf16x8* Bf) {
  __builtin_amdgcn_s_setprio(1);
  #pragma unroll
  for (int j = 0; j < 4; ++j)
    #pragma unroll
    for (int ni = 0; ni < 4; ++ni)
      accq[j][ni] = __builtin_amdgcn_mfma_f32_16x16x32_bf16(Af[j], Bf[ni], accq[j][ni], 0, 0, 0);
  __builtin_amdgcn_s_setprio(0);
}

#define STAGE_A(ktt, h, dt) { const char* g_ = gA + (ktt)*128 + (h)*64; \
  char* s_ = lA + ((dt)*2 + (h))*16384; GLD16(g_ + go0, s_ + lo0); GLD16(g_ + go1, s_ + lo1); }
#define STAGE_B(ktt, h, dt) { const char* g_ = gB + (ktt)*128 + (h)*64; \
  char* s_ = lB + ((dt)*2 + (h))*16384; GLD16(g_ + go0, s_ + lo0); GLD16(g_ + go1, s_ + lo1); }
#define VM(n) { asm volatile("s_waitcnt vmcnt(" #n ")" ::: "memory"); __builtin_amdgcn_sched_barrier(0); }
#define BAR() __builtin_amdgcn_s_barrier()

__global__ __launch_bounds__(512, 2) void k_gemm8(const u16* __restrict__ A,
                                                  const u16* __restrict__ B,
                                                  const float* __restrict__ bias,
                                                  float* __restrict__ out) {
  __shared__ __align__(16) u16 ldsA[2*2*256*32];
  __shared__ __align__(16) u16 ldsB[2*2*256*32];
  int bid = blockIdx.x;                       // 0..511 ; 512 % 8 == 0 -> simple XCD swizzle ok
  int swz = (bid & 7) * 64 + (bid >> 3);
  int mt = swz >> 3, nt = swz & 7;
  int m0 = mt * 256, n0 = nt * 256;
  int tid = threadIdx.x;
  int w = tid >> 6, l = tid & 63;
  int wr = w >> 2, wc = w & 3;                // 2 x 4 waves
  int lr = l & 15, lk = l >> 4;
  const char* gA = (const char*)A + (size_t)m0 * 8192;   // row stride 4096*2B
  const char* gB = (const char*)B + (size_t)n0 * 8192;
  char* lA = (char*)ldsA;
  char* lB = (char*)ldsB;

  // staging address precompute (2 gld rounds per 16 KiB half-tile)
  int ch0 = w*64 + l, ch1 = 512 + w*64 + l;              // 16B chunk ids
  size_t go0 = (size_t)(ch0 >> 2) * 8192 + (size_t)((((ch0 & 3) ^ ((ch0 >> 4) & 3))) << 4);
  size_t go1 = (size_t)(ch1 >> 2) * 8192 + (size_t)((((ch1 & 3) ^ ((ch1 >> 4) & 3))) << 4);
  int lo0 = w * 1024, lo1 = 8192 + w * 1024;             // wave-uniform LDS bases

  // fragment read offsets (within one 16 KiB half-buffer), swizzled
  int rsw = (lr >> 2) & 3;
  int aoff = (wr*128 + lr) * 64 + ((lk ^ rsw) << 4);     // + (quad*64 + i*16)*64
  int boff = (wc*64  + lr) * 64 + ((lk ^ rsw) << 4);     // + ni*16*64

  f32x4 acc[8][4];
  #pragma unroll
  for (int mi = 0; mi < 8; ++mi)
    #pragma unroll
    for (int ni = 0; ni < 4; ++ni)
      #pragma unroll
      for (int e = 0; e < 4; ++e) acc[mi][ni][e] = 0.f;

  // prologue: tile0 (both halves) + tile1 (k-half 0) = 12 loads
  STAGE_A(0, 0, 0); STAGE_B(0, 0, 0);
  STAGE_A(0, 1, 0); STAGE_B(0, 1, 0);
  STAGE_A(1, 0, 1); STAGE_B(1, 0, 1);
  VM(8);                        // oldest 4 loads (tile0 k-half0 A+B) landed
  BAR();

  const int NT = 64;            // 4096 / 64
  // ---- main loop: kt = 0..NT-3 (full staging; steady-state vmcnt(8) exact) ----
  for (int kt = 0; kt < NT-2; ++kt) {
    int d = kt & 1, dn = d ^ 1;
    int h0 = (d*2 + 0) * 16384, h1 = (d*2 + 1) * 16384;
    bf16x8 Af[4], Bf[4];
    // phase 0: k-half 0, m-quadrant 0
    read4(Bf, lB + h0 + boff);
    read4(Af, lA + h0 + aoff);
    STAGE_A(kt+1, 1, dn);
    BAR();
    mfma16(&acc[0], Af, Bf);
    BAR();
    // phase 1: k-half 0, m-quadrant 1
    read4(Af, lA + h0 + aoff + 4096);
    STAGE_B(kt+1, 1, dn);
    BAR();
    mfma16(&acc[4], Af, Bf);
    VM(8);                      // tile(kt) h1 landed (8 newer loads in flight)
    BAR();
    // phase 2: k-half 1, m-quadrant 0
    read4(Bf, lB + h1 + boff);
    read4(Af, lA + h1 + aoff);
    STAGE_A(kt+2, 0, d);
    BAR();
    mfma16(&acc[0], Af, Bf);
    BAR();
    // phase 3: k-half 1, m-quadrant 1
    read4(Af, lA + h1 + aoff + 4096);
    STAGE_B(kt+2, 0, d);
    BAR();
    mfma16(&acc[4], Af, Bf);
    VM(8);                      // tile(kt+1) h0 landed
    BAR();
  }
  // ---- kt = NT-2 (62): stage only tile63 h1; tail guards vmcnt(8) then vmcnt(4) ----
  {
    const int kt = NT-2;
    int d = kt & 1, dn = d ^ 1;
    int h0 = (d*2 + 0) * 16384, h1 = (d*2 + 1) * 16384;
    bf16x8 Af[4], Bf[4];
    read4(Bf, lB + h0 + boff);
    read4(Af, lA + h0 + aoff);
    STAGE_A(kt+1, 1, dn);
    BAR();
    mfma16(&acc[0], Af, Bf);
    BAR();
    read4(Af, lA + h0 + aoff + 4096);
    STAGE_B(kt+1, 1, dn);
    BAR();
    mfma16(&acc[4], Af, Bf);
    VM(8);                      // tile62 h1: exactly 8 newer loads (t63h0 + t63h1)
    BAR();
    read4(Bf, lB + h1 + boff);
    read4(Af, lA + h1 + aoff);
    BAR();
    mfma16(&acc[0], Af, Bf);
    BAR();
    read4(Af, lA + h1 + aoff + 4096);
    BAR();
    mfma16(&acc[4], Af, Bf);
    VM(4);                      // tile63 h0: only 4 newer loads (t63h1) — NOT vmcnt(8)
    BAR();
  }
  // ---- kt = NT-1 (63): no staging; vmcnt(0) before k-half 1 ----
  {
    const int kt = NT-1;
    int d = kt & 1;
    int h0 = (d*2 + 0) * 16384, h1 = (d*2 + 1) * 16384;
    bf16x8 Af[4], Bf[4];
    read4(Bf, lB + h0 + boff);
    read4(Af, lA + h0 + aoff);
    BAR();
    mfma16(&acc[0], Af, Bf);
    BAR();
    read4(Af, lA + h0 + aoff + 4096);
    BAR();
    mfma16(&acc[4], Af, Bf);
    VM(0);                      // tile63 h1 is the newest in-flight set — full drain
    BAR();
    read4(Bf, lB + h1 + boff);
    read4(Af, lA + h1 + aoff);
    BAR();
    mfma16(&acc[0], Af, Bf);
    BAR();
    read4(Af, lA + h1 + aoff + 4096);
    BAR();
    mfma16(&acc[4], Af, Bf);
  }

  // epilogue: C = acc + bias
  #pragma unroll
  for (int ni = 0; ni < 4; ++ni) {
    int col = n0 + wc*64 + ni*16 + lr;
    float bc = bias[col];
    #pragma unroll
    for (int mi = 0; mi < 8; ++mi) {
      int row = m0 + wr*128 + mi*16 + lk*4;
      #pragma unroll
      for (int e = 0; e < 4; ++e)
        out[(size_t)(row + e) * 2048 + col] = acc[mi][ni][e] + bc;
    }
  }
}

// ---------------- emergency: encode ws_size(MB) into d_out so failure is diagnosable ----------------
__global__ void k_report(float* out, float v) {
  out[blockIdx.x * 256 + threadIdx.x] = v;
}

extern "C" void kernel_launch(void* const* d_in, const int* in_sizes, int n_in,
                              void* d_out, int out_size, void* d_ws, size_t ws_size,
                              hipStream_t stream) {
  (void)in_sizes; (void)n_in; (void)out_size;
  const float* x       = (const float*)d_in[0];
  const float* gamma   = (const float*)d_in[1];
  const float* beta    = (const float*)d_in[2];
  const float* Wa      = (const float*)d_in[3];
  const float* ba      = (const float*)d_in[4];
  const float* Wh      = (const float*)d_in[5];
  const float* bh      = (const float*)d_in[6];
  const float* HpreA   = (const float*)d_in[7];
  const float* HpreH   = (const float*)d_in[8];
  const float* HresA   = (const float*)d_in[9];
  const float* HpostA  = (const float*)d_in[10];
  const float* scalesA = (const float*)d_in[11];
  const float* HresH   = (const float*)d_in[12];
  const float* HpostH  = (const float*)d_in[13];
  const float* scalesH = (const float*)d_in[14];
  const float* cm      = (const float*)d_in[15];
  float* out = (float*)d_out;

  const size_t OFF_CONST = 0;
  const size_t OFF_BIAS  = 4096;
  const size_t OFF_B     = (size_t)1 << 20;    // Wc_t bf16 [2048][4096] = 16 MiB
  const size_t OFF_A     = (size_t)17 << 20;   // A bf16 [16384][4096] = 128 MiB (first 32MiB doubles as f32 fold temp)
  const size_t NEED      = OFF_A + ((size_t)128 << 20);

  if (ws_size < NEED) {
    k_report<<<4, 256, 0, stream>>>(out, (float)(ws_size >> 20));
    return;
  }

  float* consts = (float*)((char*)d_ws + OFF_CONST);
  float* bias   = (float*)((char*)d_ws + OFF_BIAS);
  u16*   Bt     = (u16*)((char*)d_ws + OFF_B);
  u16*   Am     = (u16*)((char*)d_ws + OFF_A);
  float* temp   = (float*)((char*)d_ws + OFF_A);   // reused before Am is written

  k_prepbias<<<1, 256, 0, stream>>>(HpreA, HpreH, HresA, HpostA, scalesA,
                                    HresH, HpostH, scalesH, cm, consts, ba, bh, bias);
  k_fold<<<2048, 256, 0, stream>>>(Wa, Wh, consts, temp);
  k_transpose<<<dim3(64, 32), 256, 0, stream>>>(temp, Bt);
  k_rowprep<<<4096, 256, 0, stream>>>(x, gamma, beta, Am);   // overwrites temp area — must follow k_transpose
  k_gemm8<<<512, 512, 0, stream>>>(Am, Bt, bias, out);
}

// Round 5
// 631.660 us; speedup vs baseline: 1.0556x; 1.0172x over previous
//
#include <hip/hip_runtime.h>
#include <stdint.h>

typedef float  f32x4  __attribute__((ext_vector_type(4)));
typedef short  bf16x8 __attribute__((ext_vector_type(8)));
typedef unsigned short u16;
typedef unsigned short u16x8 __attribute__((ext_vector_type(8)));

// async global->LDS, 16B per lane; LDS dest is wave-uniform base + lane*16
#define GLD16(gsrc, ldst) \
  __builtin_amdgcn_global_load_lds((const __attribute__((address_space(1))) uint32_t*)(gsrc), \
                                   (__attribute__((address_space(3))) uint32_t*)(ldst), 16, 0, 0)

static __device__ __forceinline__ u16 f2bf(float f) {
  union { float f; uint32_t u; } v; v.f = f;
  uint32_t r = (v.u + 0x7FFFu + ((v.u >> 16) & 1u)) >> 16;  // RTNE
  return (u16)r;
}

// ---------------- P0: 4x4 matrices + alpha -> consts[80], plus folded bias [2048] ----------------
// consts[0:16]  Hpre_attn softmax (p-major [p][u])
// consts[16:32] Hpre_hyb  softmax
// consts[32:48] Rcomb[p][t] = a*sink_a[p][t] + (1-a)*sink_h[p][t]
// consts[48:64] Ca[t][s] = a*scales_a[t]*softmax(Hpost_a)[t][s]
// consts[64:80] Ch[t][s] = (1-a)*scales_h[t]*softmax(Hpost_h)[t][s]
__global__ void k_prepbias(const float* __restrict__ HpreA_l, const float* __restrict__ HpreH_l,
                           const float* __restrict__ HresA_l, const float* __restrict__ HpostA_l,
                           const float* __restrict__ scalesA,
                           const float* __restrict__ HresH_l, const float* __restrict__ HpostH_l,
                           const float* __restrict__ scalesH,
                           const float* __restrict__ crossmix, float* __restrict__ consts,
                           const float* __restrict__ bA, const float* __restrict__ bH,
                           float* __restrict__ bias) {
  __shared__ float sc[80];
  if (threadIdx.x == 0) {
    float alpha = 1.0f / (1.0f + expf(-crossmix[0]));
    float Pa[16], Ph[16], SA[16], SH[16], QA[16], QH[16];
    const float* Ls[4] = {HpreA_l, HpreH_l, HpostA_l, HpostH_l};
    float* Os[4] = {Pa, Ph, QA, QH};
    for (int m = 0; m < 4; ++m) {
      for (int r = 0; r < 4; ++r) {
        float mx = Ls[m][r*4+0];
        for (int c = 1; c < 4; ++c) mx = fmaxf(mx, Ls[m][r*4+c]);
        float s = 0.f;
        for (int c = 0; c < 4; ++c) { float e = expf(Ls[m][r*4+c] - mx); Os[m][r*4+c] = e; s += e; }
        for (int c = 0; c < 4; ++c) Os[m][r*4+c] /= s;
      }
    }
    const float* Lr[2] = {HresA_l, HresH_l};
    float* Or[2] = {SA, SH};
    for (int m = 0; m < 2; ++m) {
      float mx = Lr[m][0];
      for (int i = 1; i < 16; ++i) mx = fmaxf(mx, Lr[m][i]);
      for (int i = 0; i < 16; ++i) Or[m][i] = expf(Lr[m][i] - mx);
      for (int it = 0; it < 20; ++it) {
        for (int r = 0; r < 4; ++r) {
          float s = 1e-8f;
          for (int c = 0; c < 4; ++c) s += Or[m][r*4+c];
          for (int c = 0; c < 4; ++c) Or[m][r*4+c] /= s;
        }
        for (int c = 0; c < 4; ++c) {
          float s = 1e-8f;
          for (int r = 0; r < 4; ++r) s += Or[m][r*4+c];
          for (int r = 0; r < 4; ++r) Or[m][r*4+c] /= s;
        }
      }
    }
    for (int i = 0; i < 16; ++i) sc[i]      = Pa[i];
    for (int i = 0; i < 16; ++i) sc[16 + i] = Ph[i];
    for (int i = 0; i < 16; ++i) sc[32 + i] = alpha * SA[i] + (1.0f - alpha) * SH[i];
    for (int t = 0; t < 4; ++t)
      for (int s = 0; s < 4; ++s) {
        sc[48 + t*4 + s] = alpha * scalesA[t] * QA[t*4 + s];
        sc[64 + t*4 + s] = (1.0f - alpha) * scalesH[t] * QH[t*4 + s];
      }
    for (int i = 0; i < 80; ++i) consts[i] = sc[i];
  }
  __syncthreads();
  #pragma unroll
  for (int k = 0; k < 8; ++k) {
    int j = k*256 + threadIdx.x;     // 0..2047
    int t = j >> 9, d = j & 511;
    float acc = 0.f;
    for (int s = 0; s < 4; ++s)
      acc += sc[48 + t*4 + s] * bA[s*512 + d] + sc[64 + t*4 + s] * bH[s*512 + d];
    bias[j] = acc;
  }
}

// ---------------- P1a: fold 4x4 mixes into weights; f32 temp [4096][2048] ----------------
// temp[half*2048 + p*512 + da][t*512 + d] = sum_{u,s} Hpre[p,u] * W[u*512+da, s*512+d] * C[t,s]
//   half=1 additionally adds Rcomb[p][t] * delta(da == d)   (residual fold)
__global__ __launch_bounds__(256) void k_fold(const float* __restrict__ Wa,
                                              const float* __restrict__ Wh,
                                              const float* __restrict__ consts,
                                              float* __restrict__ temp) {
  int bid  = blockIdx.x;                 // 0..2047
  int da   = bid >> 2;                   // 0..511
  int half = (bid >> 1) & 1;
  int j4   = (bid & 1) * 256 + threadIdx.x;  // 0..511  (output col / 4)
  int t    = j4 >> 7;
  int dcol = (j4 & 127) * 4;
  const float* W  = half ? Wh : Wa;
  const float* Hp = consts + (half ? 16 : 0);
  const float* C  = consts + (half ? 64 : 48);
  float c_t[4];
  for (int s = 0; s < 4; ++s) c_t[s] = C[t*4 + s];
  f32x4 acc[4];
  for (int p = 0; p < 4; ++p) for (int e = 0; e < 4; ++e) acc[p][e] = 0.f;
  #pragma unroll
  for (int u = 0; u < 4; ++u) {
    float hp[4];
    for (int p = 0; p < 4; ++p) hp[p] = Hp[p*4 + u];
    #pragma unroll
    for (int s = 0; s < 4; ++s) {
      f32x4 wv = *(const f32x4*)&W[(size_t)(u*512 + da) * 2048 + s*512 + dcol];
      float cs = c_t[s];
      for (int p = 0; p < 4; ++p) acc[p] += (hp[p] * cs) * wv;
    }
  }
  if (half) {
    int e = da - dcol;
    if (e >= 0 && e < 4)
      for (int p = 0; p < 4; ++p) acc[p][e] += consts[32 + p*4 + t];
  }
  for (int p = 0; p < 4; ++p)
    *(f32x4*)&temp[(size_t)(half*2048 + p*512 + da) * 2048 + j4*4] = acc[p];
}

// ---------------- P1T: transpose temp [4096][2048] f32 -> Wc_t [2048][4096] bf16 ----------------
__global__ __launch_bounds__(256) void k_transpose(const float* __restrict__ temp,
                                                   u16* __restrict__ Bt) {
  __shared__ float tile[64][65];
  int r0 = blockIdx.x * 64;   // rows of temp (0..4095)
  int c0 = blockIdx.y * 64;   // cols of temp (0..2047)
  int tid = threadIdx.x;
  int lr = tid >> 4;          // 0..15
  int lc = (tid & 15) * 4;    // 0..60
  #pragma unroll
  for (int i = 0; i < 4; ++i) {
    int row = lr + i * 16;
    f32x4 v = *(const f32x4*)&temp[(size_t)(r0 + row) * 2048 + c0 + lc];
    tile[row][lc+0] = v[0]; tile[row][lc+1] = v[1];
    tile[row][lc+2] = v[2]; tile[row][lc+3] = v[3];
  }
  __syncthreads();
  #pragma unroll
  for (int k = 0; k < 4; ++k) {
    int jj = lr + k * 16;     // col of temp = row of Bt
    ushort4 o;
    o.x = f2bf(tile[lc+0][jj]); o.y = f2bf(tile[lc+1][jj]);
    o.z = f2bf(tile[lc+2][jj]); o.w = f2bf(tile[lc+3][jj]);
    *(ushort4*)&Bt[(size_t)(c0 + jj) * 4096 + r0 + lc] = o;
  }
}

// ---------------- P2: per-row LN + materialize A bf16 [16384][4096] ----------------
// Wave-per-row: no LDS, no __syncthreads. cols 0..2047 = LN(x), 2048..4095 = raw x.
__global__ __launch_bounds__(256) void k_rowprep(const float* __restrict__ x,
                                                 const float* __restrict__ gamma,
                                                 const float* __restrict__ beta,
                                                 u16* __restrict__ A) {
  int wid = (blockIdx.x * 256 + threadIdx.x) >> 6;   // 0..16383 (row)
  int l = threadIdx.x & 63;
  const float* row = x + (size_t)wid * 2048;
  f32x4 v[8];
  float s1 = 0.f, s2 = 0.f;
  #pragma unroll
  for (int j = 0; j < 8; ++j) {
    v[j] = *(const f32x4*)&row[j*256 + l*4];
    #pragma unroll
    for (int e = 0; e < 4; ++e) { s1 += v[j][e]; s2 += v[j][e]*v[j][e]; }
  }
  #pragma unroll
  for (int off = 32; off; off >>= 1) {
    s1 += __shfl_down(s1, off, 64);
    s2 += __shfl_down(s2, off, 64);
  }
  s1 = __shfl(s1, 0, 64);
  s2 = __shfl(s2, 0, 64);
  float mu   = s1 * (1.0f/2048.0f);
  float var  = s2 * (1.0f/2048.0f) - mu*mu;
  float rstd = rsqrtf(var + 1e-5f);
  u16* An = A + (size_t)wid * 4096;
  #pragma unroll
  for (int j = 0; j < 8; ++j) {
    f32x4 g = *(const f32x4*)&gamma[j*256 + l*4];
    f32x4 b = *(const f32x4*)&beta[j*256 + l*4];
    ushort4 pn, pr;
    pn.x = f2bf((v[j][0]-mu)*rstd*g[0] + b[0]);
    pn.y = f2bf((v[j][1]-mu)*rstd*g[1] + b[1]);
    pn.z = f2bf((v[j][2]-mu)*rstd*g[2] + b[2]);
    pn.w = f2bf((v[j][3]-mu)*rstd*g[3] + b[3]);
    pr.x = f2bf(v[j][0]); pr.y = f2bf(v[j][1]);
    pr.z = f2bf(v[j][2]); pr.w = f2bf(v[j][3]);
    *(ushort4*)&An[j*256 + l*4]        = pn;   // normed half (K 0..2047)
    *(ushort4*)&An[2048 + j*256 + l*4] = pr;   // raw half    (K 2048..4095)
  }
}

// ---------------- GEMM: 256x256 tile, BK=64, 8-phase schedule (T1+T2+T3/T4+T5) ----------------
// out[16384][2048] = A[16384][4096] @ Bt^T + bias.  Bt is [2048][4096] (N-major).
// 512 threads = 8 waves (2 M x 4 N), wave tile 128x64, 16x16x32 bf16 MFMA.
// LDS: per operand 2 dbuf x 2 K-halves x [256 rows][32 k] bf16 (16 KiB each) = 64 KiB; total 128 KiB.
//
// Swizzle (R4 fix): bank group of (row r, chunk c) = 16*(r&1) + 4*c. For 8 consecutive
// rows (one LDS service group: 8 lanes x 16B = 128B = all 32 banks) the chunk permutation
// must make (r&1, c) pairs all-distinct: c ^= (r>>1)&3. R4's (r>>2)&3 was constant over
// 4-row pairs sharing parity -> 2-way conflict, counter unchanged (2.52e7, 4 cyc/read).
// Applied to the pre-swizzled global SOURCE (global_load_lds writes linearly; row = ch>>2
// -> f = (ch>>3)&3) and to the ds_read chunk (f = (lr>>1)&3) — same involution both sides.
//
// vmcnt ledger: steady state keeps 8 loads (4 half-tile STAGE pairs) in flight past each guard;
// tail peeled: kt=62 guards are vmcnt(8)/vmcnt(4), kt=63 is vmcnt(0)/none (race fix, R3 audit).

static __device__ __forceinline__ void read4(bf16x8* F, const char* base) {
  #pragma unroll
  for (int i = 0; i < 4; ++i) F[i] = *(const bf16x8*)(base + i*1024);
}
static __device__ __forceinline__ void mfma16(f32x4 (*accq)[4], const bf16x8* Af, const bf16x8* Bf) {
  __builtin_amdgcn_s_setprio(1);
  #pragma unroll
  for (int j = 0; j < 4; ++j)
    #pragma unroll
    for (int ni = 0; ni < 4; ++ni)
      accq[j][ni] = __builtin_amdgcn_mfma_f32_16x16x32_bf16(Af[j], Bf[ni], accq[j][ni], 0, 0, 0);
  __builtin_amdgcn_s_setprio(0);
}

#define STAGE_A(ktt, h, dt) { const char* g_ = gA + (ktt)*128 + (h)*64; \
  char* s_ = lA + ((dt)*2 + (h))*16384; GLD16(g_ + go0, s_ + lo0); GLD16(g_ + go1, s_ + lo1); }
#define STAGE_B(ktt, h, dt) { const char* g_ = gB + (ktt)*128 + (h)*64; \
  char* s_ = lB + ((dt)*2 + (h))*16384; GLD16(g_ + go0, s_ + lo0); GLD16(g_ + go1, s_ + lo1); }
#define VM(n) { asm volatile("s_waitcnt vmcnt(" #n ")" ::: "memory"); __builtin_amdgcn_sched_barrier(0); }
#define BAR() __builtin_amdgcn_s_barrier()

__global__ __launch_bounds__(512, 2) void k_gemm8(const u16* __restrict__ A,
                                                  const u16* __restrict__ B,
                                                  const float* __restrict__ bias,
                                                  float* __restrict__ out) {
  __shared__ __align__(16) u16 ldsA[2*2*256*32];
  __shared__ __align__(16) u16 ldsB[2*2*256*32];
  int bid = blockIdx.x;                       // 0..511 ; 512 % 8 == 0 -> simple XCD swizzle ok
  int swz = (bid & 7) * 64 + (bid >> 3);
  int mt = swz >> 3, nt = swz & 7;
  int m0 = mt * 256, n0 = nt * 256;
  int tid = threadIdx.x;
  int w = tid >> 6, l = tid & 63;
  int wr = w >> 2, wc = w & 3;                // 2 x 4 waves
  int lr = l & 15, lk = l >> 4;
  const char* gA = (const char*)A + (size_t)m0 * 8192;   // row stride 4096*2B
  const char* gB = (const char*)B + (size_t)n0 * 8192;
  char* lA = (char*)ldsA;
  char* lB = (char*)ldsB;

  // staging address precompute (2 gld rounds per 16 KiB half-tile)
  // source pre-swizzle: LDS chunk (r = ch>>2, c = ch&3) receives global chunk c ^ ((ch>>3)&3)
  int ch0 = w*64 + l, ch1 = 512 + w*64 + l;              // 16B chunk ids
  size_t go0 = (size_t)(ch0 >> 2) * 8192 + (size_t)((((ch0 & 3) ^ ((ch0 >> 3) & 3))) << 4);
  size_t go1 = (size_t)(ch1 >> 2) * 8192 + (size_t)((((ch1 & 3) ^ ((ch1 >> 3) & 3))) << 4);
  int lo0 = w * 1024, lo1 = 8192 + w * 1024;             // wave-uniform LDS bases

  // fragment read offsets (within one 16 KiB half-buffer), swizzled with the same involution:
  // row = (quad-base multiple of 16) + lr  ->  f(row) = (lr>>1)&3
  int rsw = (lr >> 1) & 3;
  int aoff = (wr*128 + lr) * 64 + ((lk ^ rsw) << 4);     // + (quad*64 + i*16)*64
  int boff = (wc*64  + lr) * 64 + ((lk ^ rsw) << 4);     // + ni*16*64

  f32x4 acc[8][4];
  #pragma unroll
  for (int mi = 0; mi < 8; ++mi)
    #pragma unroll
    for (int ni = 0; ni < 4; ++ni)
      #pragma unroll
      for (int e = 0; e < 4; ++e) acc[mi][ni][e] = 0.f;

  // prologue: tile0 (both halves) + tile1 (k-half 0) = 12 loads
  STAGE_A(0, 0, 0); STAGE_B(0, 0, 0);
  STAGE_A(0, 1, 0); STAGE_B(0, 1, 0);
  STAGE_A(1, 0, 1); STAGE_B(1, 0, 1);
  VM(8);                        // oldest 4 loads (tile0 k-half0 A+B) landed
  BAR();

  const int NT = 64;            // 4096 / 64
  // ---- main loop: kt = 0..NT-3 (full staging; steady-state vmcnt(8) exact) ----
  for (int kt = 0; kt < NT-2; ++kt) {
    int d = kt & 1, dn = d ^ 1;
    int h0 = (d*2 + 0) * 16384, h1 = (d*2 + 1) * 16384;
    bf16x8 Af[4], Bf[4];
    // phase 0: k-half 0, m-quadrant 0
    read4(Bf, lB + h0 + boff);
    read4(Af, lA + h0 + aoff);
    STAGE_A(kt+1, 1, dn);
    BAR();
    mfma16(&acc[0], Af, Bf);
    BAR();
    // phase 1: k-half 0, m-quadrant 1
    read4(Af, lA + h0 + aoff + 4096);
    STAGE_B(kt+1, 1, dn);
    BAR();
    mfma16(&acc[4], Af, Bf);
    VM(8);                      // tile(kt) h1 landed (8 newer loads in flight)
    BAR();
    // phase 2: k-half 1, m-quadrant 0
    read4(Bf, lB + h1 + boff);
    read4(Af, lA + h1 + aoff);
    STAGE_A(kt+2, 0, d);
    BAR();
    mfma16(&acc[0], Af, Bf);
    BAR();
    // phase 3: k-half 1, m-quadrant 1
    read4(Af, lA + h1 + aoff + 4096);
    STAGE_B(kt+2, 0, d);
    BAR();
    mfma16(&acc[4], Af, Bf);
    VM(8);                      // tile(kt+1) h0 landed
    BAR();
  }
  // ---- kt = NT-2 (62): stage only tile63 h1; tail guards vmcnt(8) then vmcnt(4) ----
  {
    const int kt = NT-2;
    int d = kt & 1, dn = d ^ 1;
    int h0 = (d*2 + 0) * 16384, h1 = (d*2 + 1) * 16384;
    bf16x8 Af[4], Bf[4];
    read4(Bf, lB + h0 + boff);
    read4(Af, lA + h0 + aoff);
    STAGE_A(kt+1, 1, dn);
    BAR();
    mfma16(&acc[0], Af, Bf);
    BAR();
    read4(Af, lA + h0 + aoff + 4096);
    STAGE_B(kt+1, 1, dn);
    BAR();
    mfma16(&acc[4], Af, Bf);
    VM(8);                      // tile62 h1: exactly 8 newer loads (t63h0 + t63h1)
    BAR();
    read4(Bf, lB + h1 + boff);
    read4(Af, lA + h1 + aoff);
    BAR();
    mfma16(&acc[0], Af, Bf);
    BAR();
    read4(Af, lA + h1 + aoff + 4096);
    BAR();
    mfma16(&acc[4], Af, Bf);
    VM(4);                      // tile63 h0: only 4 newer loads (t63h1) — NOT vmcnt(8)
    BAR();
  }
  // ---- kt = NT-1 (63): no staging; vmcnt(0) before k-half 1 ----
  {
    const int kt = NT-1;
    int d = kt & 1;
    int h0 = (d*2 + 0) * 16384, h1 = (d*2 + 1) * 16384;
    bf16x8 Af[4], Bf[4];
    read4(Bf, lB + h0 + boff);
    read4(Af, lA + h0 + aoff);
    BAR();
    mfma16(&acc[0], Af, Bf);
    BAR();
    read4(Af, lA + h0 + aoff + 4096);
    BAR();
    mfma16(&acc[4], Af, Bf);
    VM(0);                      // tile63 h1 is the newest in-flight set — full drain
    BAR();
    read4(Bf, lB + h1 + boff);
    read4(Af, lA + h1 + aoff);
    BAR();
    mfma16(&acc[0], Af, Bf);
    BAR();
    read4(Af, lA + h1 + aoff + 4096);
    BAR();
    mfma16(&acc[4], Af, Bf);
  }

  // epilogue: C = acc + bias
  #pragma unroll
  for (int ni = 0; ni < 4; ++ni) {
    int col = n0 + wc*64 + ni*16 + lr;
    float bc = bias[col];
    #pragma unroll
    for (int mi = 0; mi < 8; ++mi) {
      int row = m0 + wr*128 + mi*16 + lk*4;
      #pragma unroll
      for (int e = 0; e < 4; ++e)
        out[(size_t)(row + e) * 2048 + col] = acc[mi][ni][e] + bc;
    }
  }
}

// ---------------- emergency: encode ws_size(MB) into d_out so failure is diagnosable ----------------
__global__ void k_report(float* out, float v) {
  out[blockIdx.x * 256 + threadIdx.x] = v;
}

extern "C" void kernel_launch(void* const* d_in, const int* in_sizes, int n_in,
                              void* d_out, int out_size, void* d_ws, size_t ws_size,
                              hipStream_t stream) {
  (void)in_sizes; (void)n_in; (void)out_size;
  const float* x       = (const float*)d_in[0];
  const float* gamma   = (const float*)d_in[1];
  const float* beta    = (const float*)d_in[2];
  const float* Wa      = (const float*)d_in[3];
  const float* ba      = (const float*)d_in[4];
  const float* Wh      = (const float*)d_in[5];
  const float* bh      = (const float*)d_in[6];
  const float* HpreA   = (const float*)d_in[7];
  const float* HpreH   = (const float*)d_in[8];
  const float* HresA   = (const float*)d_in[9];
  const float* HpostA  = (const float*)d_in[10];
  const float* scalesA = (const float*)d_in[11];
  const float* HresH   = (const float*)d_in[12];
  const float* HpostH  = (const float*)d_in[13];
  const float* scalesH = (const float*)d_in[14];
  const float* cm      = (const float*)d_in[15];
  float* out = (float*)d_out;

  const size_t OFF_CONST = 0;
  const size_t OFF_BIAS  = 4096;
  const size_t OFF_B     = (size_t)1 << 20;    // Wc_t bf16 [2048][4096] = 16 MiB
  const size_t OFF_A     = (size_t)17 << 20;   // A bf16 [16384][4096] = 128 MiB (first 32MiB doubles as f32 fold temp)
  const size_t NEED      = OFF_A + ((size_t)128 << 20);

  if (ws_size < NEED) {
    k_report<<<4, 256, 0, stream>>>(out, (float)(ws_size >> 20));
    return;
  }

  float* consts = (float*)((char*)d_ws + OFF_CONST);
  float* bias   = (float*)((char*)d_ws + OFF_BIAS);
  u16*   Bt     = (u16*)((char*)d_ws + OFF_B);
  u16*   Am     = (u16*)((char*)d_ws + OFF_A);
  float* temp   = (float*)((char*)d_ws + OFF_A);   // reused before Am is written

  k_prepbias<<<1, 256, 0, stream>>>(HpreA, HpreH, HresA, HpostA, scalesA,
                                    HresH, HpostH, scalesH, cm, consts, ba, bh, bias);
  k_fold<<<2048, 256, 0, stream>>>(Wa, Wh, consts, temp);
  k_transpose<<<dim3(64, 32), 256, 0, stream>>>(temp, Bt);
  k_rowprep<<<4096, 256, 0, stream>>>(x, gamma, beta, Am);   // overwrites temp area — must follow k_transpose
  k_gemm8<<<512, 512, 0, stream>>>(Am, Bt, bias, out);
}